// Round 12
// baseline (226.941 us; speedup 1.0000x reference)
//
#include <hip/hip_runtime.h>

#define NROW 8192
#define FIN  512
#define FOUT 256
#define ALPHA 0.2f

typedef float  f32x4  __attribute__((ext_vector_type(4)));
typedef int    i32x4  __attribute__((ext_vector_type(4)));
typedef __bf16 bf16x8 __attribute__((ext_vector_type(8)));
typedef __bf16 bf16x4 __attribute__((ext_vector_type(4)));

// Raw workgroup barrier WITHOUT the vmcnt(0) drain __syncthreads would emit.
__device__ __forceinline__ void bar_lds() {
    asm volatile("s_waitcnt lgkmcnt(0)" ::: "memory");
    __builtin_amdgcn_sched_barrier(0);          // rule 18
    __builtin_amdgcn_s_barrier();
}

// ---------------- K1: WbT[f][k] = bf16(W[k][f]) ----------------
__global__ void k1_wt(const float* __restrict__ W, unsigned short* __restrict__ WbT_u) {
    __bf16* WbT = (__bf16*)WbT_u;
    __shared__ float tw[32][33];
    int bx = blockIdx.x & 7;
    int by = blockIdx.x >> 3;
    int f0 = bx * 32, k0 = by * 32;
    int tx = threadIdx.x & 31, ty = threadIdx.x >> 5;
#pragma unroll
    for (int r = 0; r < 4; ++r)
        tw[ty + 8*r][tx] = W[(k0 + ty + 8*r) * FOUT + f0 + tx];
    __syncthreads();
#pragma unroll
    for (int r = 0; r < 4; ++r)
        WbT[(f0 + ty + 8*r) * FIN + k0 + tx] = (__bf16)tw[tx][ty + 8*r];
}

// ---------------- K2: h = x@W  + FUSED l1/l2 (exact, f32 acc) + mean_h partials ----------------
__global__ __launch_bounds__(256, 2) void k2_gemm1(const float* __restrict__ x,
                                                   const unsigned short* __restrict__ WbT_u,
                                                   const float* __restrict__ a1,
                                                   const float* __restrict__ a2,
                                                   unsigned short* __restrict__ hTb_u,
                                                   float* __restrict__ l1,
                                                   float* __restrict__ l2,
                                                   float* __restrict__ mean_sum) {
    const __bf16* WbT = (const __bf16*)WbT_u;
    __bf16* hTb = (__bf16*)hTb_u;
    int i0 = blockIdx.x * 32;
    int t = threadIdx.x;
    int lane = t & 63, wv = t >> 6;
    int lm = lane & 15, lg = lane >> 4;
    int wf0 = wv * 64;

    f32x4 acc[4][2];
#pragma unroll
    for (int a = 0; a < 4; ++a)
#pragma unroll
        for (int b = 0; b < 2; ++b) acc[a][b] = (f32x4){0.f, 0.f, 0.f, 0.f};

    for (int kt = 0; kt < FIN; kt += 32) {
        bf16x8 af[4];
#pragma unroll
        for (int fi = 0; fi < 4; ++fi)
            af[fi] = *(const bf16x8*)(WbT + (wf0 + fi*16 + lm) * FIN + kt + lg*8);
        bf16x8 bfr[2];
#pragma unroll
        for (int ii = 0; ii < 2; ++ii) {
            const float* xp = x + (i0 + ii*16 + lm) * FIN + kt + lg*8;
            f32x4 v0 = *(const f32x4*)(xp);
            f32x4 v1 = *(const f32x4*)(xp + 4);
            bf16x8 b;
#pragma unroll
            for (int e = 0; e < 4; ++e) { b[e] = (__bf16)v0[e]; b[4+e] = (__bf16)v1[e]; }
            bfr[ii] = b;
        }
#pragma unroll
        for (int fi = 0; fi < 4; ++fi)
#pragma unroll
            for (int ii = 0; ii < 2; ++ii)
                acc[fi][ii] = __builtin_amdgcn_mfma_f32_16x16x32_bf16(af[fi], bfr[ii], acc[fi][ii], 0, 0, 0);
    }

    // ---- write hTb (D layout m89: f = wf0+fi*16+lg*4+q ; i = i0+ii*16+lm) ----
#pragma unroll
    for (int fi = 0; fi < 4; ++fi)
#pragma unroll
        for (int ii = 0; ii < 2; ++ii)
#pragma unroll
            for (int q = 0; q < 4; ++q)
                hTb[(wf0 + fi*16 + lg*4 + q) * NROW + i0 + ii*16 + lm] = (__bf16)acc[fi][ii][q];

    // ---- fused epilogue: l1/l2 (exact) + mean_h partials ----
    float s1[2] = {0.f, 0.f}, s2[2] = {0.f, 0.f};
    float mh[4][4];
#pragma unroll
    for (int fi = 0; fi < 4; ++fi)
#pragma unroll
        for (int q = 0; q < 4; ++q) {
            int f = wf0 + fi*16 + lg*4 + q;
            float a1v = a1[f], a2v = a2[f];
            float h0 = acc[fi][0][q], h1 = acc[fi][1][q];
            s1[0] += h0 * a1v; s1[1] += h1 * a1v;
            s2[0] += h0 * a2v; s2[1] += h1 * a2v;
            mh[fi][q] = h0 + h1;
        }
    // reduce l-partials across lg (lane bits 4,5)
#pragma unroll
    for (int d = 16; d < 64; d <<= 1) {
        s1[0] += __shfl_xor(s1[0], d); s1[1] += __shfl_xor(s1[1], d);
        s2[0] += __shfl_xor(s2[0], d); s2[1] += __shfl_xor(s2[1], d);
    }
    __shared__ float redA[4][2][16], redB[4][2][16];
    if (lg == 0) {
        redA[wv][0][lm] = s1[0]; redA[wv][1][lm] = s1[1];
        redB[wv][0][lm] = s2[0]; redB[wv][1][lm] = s2[1];
    }
    // mean partials: reduce across lm (lane bits 0..3), then atomicAdd
#pragma unroll
    for (int fi = 0; fi < 4; ++fi)
#pragma unroll
        for (int q = 0; q < 4; ++q) {
#pragma unroll
            for (int d = 1; d < 16; d <<= 1) mh[fi][q] += __shfl_xor(mh[fi][q], d);
        }
    if (lm == 0) {
#pragma unroll
        for (int fi = 0; fi < 4; ++fi)
#pragma unroll
            for (int q = 0; q < 4; ++q)
                atomicAdd(&mean_sum[wf0 + fi*16 + lg*4 + q], mh[fi][q]);
    }
    __syncthreads();
    if (t < 32) {
        int ii = t >> 4, l = t & 15;
        l1[i0 + ii*16 + l] = redA[0][ii][l] + redA[1][ii][l] + redA[2][ii][l] + redA[3][ii][l];
    } else if (t < 64) {
        int tt2 = t - 32;
        int ii = tt2 >> 4, l = tt2 & 15;
        l2[i0 + ii*16 + l] = redB[0][ii][l] + redB[1][ii][l] + redB[2][ii][l] + redB[3][ii][l];
    }
}

// ---------------- K4: fused masked-softmax-weighted GEMM (r11 structure, raw barriers) ----------------
__global__ __launch_bounds__(256, 2) void k4_attn(const int* __restrict__ adj,
                                                  const unsigned short* __restrict__ hTb_u,
                                                  const float* __restrict__ l1,
                                                  const float* __restrict__ l2,
                                                  float* __restrict__ outpT,
                                                  float* __restrict__ Zp,
                                                  int js, int jwidth, int ntiles) {
    const __bf16* hTb = (const __bf16*)hTb_u;
    __shared__ __align__(16) __bf16 wlds[2][64 * 64];

    int b = blockIdx.x;
    int js_idx = b % js;
    int it = b / js;
    int i0 = it * 64;
    int jstart = js_idx * jwidth;

    int t = threadIdx.x;
    int lane = t & 63, wv = t >> 6;
    int lm = lane & 15, lg = lane >> 4;
    int wf0 = wv * 64;
    int r = t >> 2, cc = t & 3;
    int i_glob = i0 + r;
    float l1v = l1[i_glob];

    const i32x4* adj4 = (const i32x4*)adj;
    const f32x4* l24  = (const f32x4*)l2;
    long arow = (long)i_glob * (NROW / 4);

    f32x4 acc[4][4];
#pragma unroll
    for (int a = 0; a < 4; ++a)
#pragma unroll
        for (int c = 0; c < 4; ++c) acc[a][c] = (f32x4){0.f, 0.f, 0.f, 0.f};
    float zpart = 0.f;

    i32x4 adjA[4], adjB[4];

    auto loadT = [&](i32x4 (&adjR)[4], int jb) {
        int c4 = jb >> 2;
#pragma unroll
        for (int k = 0; k < 4; ++k)
            adjR[k] = adj4[arow + c4 + cc + 4*k];
    };

    auto stageT = [&](int bufi, i32x4 (&adjR)[4], int jb) {
        int c4 = jb >> 2;
        __bf16* wl = wlds[bufi];
        float zadd = 0.f;
#pragma unroll
        for (int k = 0; k < 4; ++k) {
            f32x4 l2v = l24[c4 + cc + 4*k];
            int jl = cc * 4 + 16 * k;
            bf16x4 p;
#pragma unroll
            for (int e = 0; e < 4; ++e) {
                float s = l1v + l2v[e];
                float ex = __expf(fmaxf(s, ALPHA * s));
                float w = (adjR[k][e] > 0) ? ex : 0.0f;
                __bf16 wb = (__bf16)w;
                p[e] = wb;
                zadd += (float)wb;
            }
            int blk = jl >> 3;
            int eo = r * 64 + ((blk ^ (r & 7)) << 3) + (jl & 7);   // XOR swizzle (G4)
            *(bf16x4*)(wl + eo) = p;
        }
        zpart += zadd;
    };

    auto mfmaT = [&](int bufi, int jb) {
        const __bf16* wl = wlds[bufi];
        bf16x8 af[2][4];
#pragma unroll
        for (int ks = 0; ks < 2; ++ks)
#pragma unroll
            for (int fi = 0; fi < 4; ++fi)
                af[ks][fi] = *(const bf16x8*)(hTb + (wf0 + fi*16 + lm) * NROW + jb + ks*32 + lg*8);
#pragma unroll
        for (int ks = 0; ks < 2; ++ks) {
            bf16x8 bw[4];
#pragma unroll
            for (int ii = 0; ii < 4; ++ii) {
                int row = ii * 16 + lm;
                int blk = ks * 4 + lg;
                bw[ii] = *(const bf16x8*)(wl + row * 64 + ((blk ^ (row & 7)) << 3));
            }
#pragma unroll
            for (int fi = 0; fi < 4; ++fi)
#pragma unroll
                for (int ii = 0; ii < 4; ++ii)
                    acc[fi][ii] = __builtin_amdgcn_mfma_f32_16x16x32_bf16(af[ks][fi], bw[ii], acc[fi][ii], 0, 0, 0);
        }
    };

    loadT(adjA, jstart);
    stageT(0, adjA, jstart);
    loadT(adjB, jstart + 64);
    bar_lds();
    for (int tt = 0; tt < ntiles; tt += 2) {
        if (tt + 2 < ntiles) loadT(adjA, jstart + (tt + 2) * 64);
        stageT(1, adjB, jstart + (tt + 1) * 64);
        mfmaT(0, jstart + tt * 64);
        bar_lds();
        if (tt + 3 < ntiles) loadT(adjB, jstart + (tt + 3) * 64);
        if (tt + 2 < ntiles) stageT(0, adjA, jstart + (tt + 2) * 64);
        mfmaT(1, jstart + (tt + 1) * 64);
        bar_lds();
    }

    float zs = zpart + __shfl_xor(zpart, 1);
    zs += __shfl_xor(zs, 2);
    if (cc == 0) Zp[js_idx * NROW + i_glob] = zs;

#pragma unroll
    for (int fi = 0; fi < 4; ++fi)
#pragma unroll
        for (int ii = 0; ii < 4; ++ii)
#pragma unroll
            for (int q = 0; q < 4; ++q)
                outpT[(long)js_idx * (NROW * FOUT) + (wf0 + fi*16 + lg*4 + q) * NROW + i0 + ii*16 + lm] = acc[fi][ii][q];
}

// ---------------- K5: combine partials + global term + softmax div + elu + transpose ----------------
__global__ void k5_final(const float* __restrict__ outpT, const float* __restrict__ Zp,
                         const float* __restrict__ l1, const float* __restrict__ mean_sum,
                         const float* __restrict__ a2, float* __restrict__ out, int js) {
    __shared__ float tile[64][65];
    __shared__ float red[4];
    __shared__ float s_mda2;
    const float inv_n = 1.0f / NROW;
    int b = blockIdx.x;
    int it = b >> 2, ft = b & 3;
    int i0 = it * 64, f0 = ft * 64;
    int t = threadIdx.x;

    float v = mean_sum[t] * inv_n * a2[t];
#pragma unroll
    for (int m = 1; m < 64; m <<= 1) v += __shfl_xor(v, m);
    if ((t & 63) == 0) red[t >> 6] = v;
    __syncthreads();
    if (t == 0) s_mda2 = red[0] + red[1] + red[2] + red[3];

    {
        int fl = t >> 2, icb = (t & 3) * 16;
#pragma unroll
        for (int c = 0; c < 4; ++c) {
            f32x4 vv = (f32x4){0.f, 0.f, 0.f, 0.f};
            for (int s = 0; s < js; ++s) {
                f32x4 u = *(const f32x4*)(outpT + (long)s * (NROW * FOUT) + (f0 + fl) * NROW + i0 + icb + 4*c);
                vv += u;
            }
#pragma unroll
            for (int e = 0; e < 4; ++e) tile[fl][icb + 4*c + e] = vv[e];
        }
    }
    __syncthreads();
    int il = t >> 2, fcb = (t & 3) * 16;
    int i = i0 + il;
    float g = l1[i] + s_mda2;
    float egi = __expf(fmaxf(g, ALPHA * g));
    float z = egi;
    for (int s = 0; s < js; ++s) z += Zp[s * NROW + i];
#pragma unroll
    for (int c = 0; c < 4; ++c) {
        f32x4 o;
#pragma unroll
        for (int e = 0; e < 4; ++e) {
            int fl = fcb + 4*c + e;
            float num = tile[fl][il] + egi * (mean_sum[f0 + fl] * inv_n);
            float val = num / z;
            o[e] = val > 0.f ? val : (__expf(val) - 1.0f);
        }
        *(f32x4*)(out + (long)i * FOUT + f0 + fcb + 4*c) = o;
    }
}

// ---------------- host ----------------
extern "C" void kernel_launch(void* const* d_in, const int* in_sizes, int n_in,
                              void* d_out, int out_size, void* d_ws, size_t ws_size,
                              hipStream_t stream) {
    const float* x   = (const float*)d_in[0];
    const int*   adj = (const int*)d_in[1];
    const float* W   = (const float*)d_in[2];
    const float* a1  = (const float*)d_in[3];
    const float* a2  = (const float*)d_in[4];
    float* out = (float*)d_out;
    char* ws = (char*)d_ws;

    unsigned short* hTb = (unsigned short*)(ws);                 // 4 MB
    unsigned short* WbT = (unsigned short*)(ws + 4194304);       // 256 KB
    float* l1       = (float*)(ws + 4456448);                    // 32 KB
    float* l2       = (float*)(ws + 4489216);                    // 32 KB
    float* mean_sum = (float*)(ws + 4521984);                    // 1 KB  (zeroed each call)
    float* Zp       = (float*)(ws + 4523008);                    // up to 256 KB (js<=8)
    float* outpT    = (float*)(ws + 4785152);                    // js * 8 MB

    size_t base = 4785152;
    size_t part = (size_t)NROW * FOUT * 4;
    int js = 1;
    if      (ws_size >= base + 8 * part) js = 8;
    else if (ws_size >= base + 4 * part) js = 4;
    else if (ws_size >= base + 2 * part) js = 2;
    int jwidth = NROW / js;
    int ntiles = jwidth / 64;   // js in {1,2,4,8} -> even

    hipMemsetAsync(mean_sum, 0, FOUT * sizeof(float), stream);
    hipLaunchKernelGGL(k1_wt,     dim3(128),      dim3(256), 0, stream, W, WbT);
    hipLaunchKernelGGL(k2_gemm1,  dim3(256),      dim3(256), 0, stream, x, WbT, a1, a2, hTb, l1, l2, mean_sum);
    hipLaunchKernelGGL(k4_attn,   dim3(128 * js), dim3(256), 0, stream, adj, hTb, l1, l2, outpT, Zp, js, jwidth, ntiles);
    hipLaunchKernelGGL(k5_final,  dim3(512),      dim3(256), 0, stream, outpT, Zp, l1, mean_sum, a2, out, js);
}